// Round 3
// baseline (773.694 us; speedup 1.0000x reference)
//
#include <hip/hip_runtime.h>
#include <hip/hip_bf16.h>
#include <stdint.h>

typedef __attribute__((ext_vector_type(8))) short bf16x8;
typedef __attribute__((ext_vector_type(4))) float f32x4;
typedef __attribute__((ext_vector_type(16))) float f32x16;

typedef const __attribute__((address_space(1))) void* gas_ptr;
typedef __attribute__((address_space(3))) void* lds_ptr_t;

__device__ __forceinline__ unsigned short f32_to_bf16_rtn(float x) {
    unsigned u = __float_as_uint(x);
    u += 0x7FFFu + ((u >> 16) & 1u);
    return (unsigned short)(u >> 16);
}
__device__ __forceinline__ float bf16_bits_to_f32(unsigned short h) {
    return __uint_as_float(((unsigned)h) << 16);
}

// ---------------------------------------------------------------------------
// Kernel 1: split fp32 inputs into hi/lo bf16 pairs (a = hi + lo, err ~2^-17)
// ---------------------------------------------------------------------------
__global__ __launch_bounds__(256) void split_hi_lo(
    const float* __restrict__ A, const float* __restrict__ B,
    unsigned short* __restrict__ Ahi, unsigned short* __restrict__ Alo,
    unsigned short* __restrict__ Bhi, unsigned short* __restrict__ Blo, int n4)
{
    int i = blockIdx.x * 256 + threadIdx.x;
    if (i >= n4) return;
    float4 a = ((const float4*)A)[i];
    float4 b = ((const float4*)B)[i];
    ushort4 h, l;

    h.x = f32_to_bf16_rtn(a.x); l.x = f32_to_bf16_rtn(a.x - bf16_bits_to_f32(h.x));
    h.y = f32_to_bf16_rtn(a.y); l.y = f32_to_bf16_rtn(a.y - bf16_bits_to_f32(h.y));
    h.z = f32_to_bf16_rtn(a.z); l.z = f32_to_bf16_rtn(a.z - bf16_bits_to_f32(h.z));
    h.w = f32_to_bf16_rtn(a.w); l.w = f32_to_bf16_rtn(a.w - bf16_bits_to_f32(h.w));
    ((ushort4*)Ahi)[i] = h; ((ushort4*)Alo)[i] = l;

    h.x = f32_to_bf16_rtn(b.x); l.x = f32_to_bf16_rtn(b.x - bf16_bits_to_f32(h.x));
    h.y = f32_to_bf16_rtn(b.y); l.y = f32_to_bf16_rtn(b.y - bf16_bits_to_f32(h.y));
    h.z = f32_to_bf16_rtn(b.z); l.z = f32_to_bf16_rtn(b.z - bf16_bits_to_f32(h.z));
    h.w = f32_to_bf16_rtn(b.w); l.w = f32_to_bf16_rtn(b.w - bf16_bits_to_f32(h.w));
    ((ushort4*)Bhi)[i] = h; ((ushort4*)Blo)[i] = l;
}

// ---------------------------------------------------------------------------
// Kernel 2: energies = A @ B^T via split-bf16 3-product MFMA GEMM.
// 128x128 block tile, BK=32, 256 threads = 4 waves as 2x2, each wave 64x64
// as 2x2 of mfma_f32_32x32x16_bf16.
//
// LDS: 4 buffers of 8 KB (Ahi, Alo, Bhi, Blo), each 128 rows x 32 cols bf16
// = 4 chunks of 16 B per row. XOR swizzle: LDS chunk position p (within row)
// holds data chunk p ^ ((row>>1)&3). This spreads each 16-lane ds_read_b128
// phase across all 8 bank-quads (2-way = free) instead of 8-way on 2 quads.
// global_load_lds dst is forced to base+tid*16, so the swizzle is applied by
// permuting the SOURCE chunk each lane fetches (within a 64B row window, so
// global coalescing is unchanged).
// ---------------------------------------------------------------------------
template <bool PRESPLIT>
__global__ __launch_bounds__(256) void gemm_bt_split(
    const __hip_bfloat16* __restrict__ Ahi, const __hip_bfloat16* __restrict__ Alo,
    const __hip_bfloat16* __restrict__ Bhi, const __hip_bfloat16* __restrict__ Blo,
    const float* __restrict__ Af, const float* __restrict__ Bf,
    float* __restrict__ out, int M, int N, int K)
{
    __shared__ char sm[32768];
    const int tid  = threadIdx.x;
    const int lane = tid & 63;
    const int w    = tid >> 6;
    const int bm = blockIdx.y, bn = blockIdx.x;
    const int wm = (w >> 1) * 64;   // wave row offset in block tile
    const int wn = (w & 1) * 64;    // wave col offset

    f32x16 acc[2][2] = {};

    // staging-side: thread tid owns LDS chunk (row = c&1 ? 64+tid>>2 : tid>>2,
    // pos = tid&3); it fetches source chunk (tid&3) ^ swizzle(row).
    const int srow   = tid >> 2;                       // row within half-tile
    const int sfetch = (tid & 3) ^ ((tid >> 3) & 3);   // swizzled source chunk
    // read-side
    const int arow  = lane & 31;       // row within 32x32 tile
    const int khalf = lane >> 5;       // k-half selector (0/1)
    const int sw    = (lane >> 1) & 3; // swizzle term: row bits (wm,i*32 ≡ 0 mod 4 after >>1)

    for (int k0 = 0; k0 < K; k0 += 32) {
        __syncthreads();
        if (PRESPLIT) {
#pragma unroll
            for (int c = 0; c < 8; ++c) {
                const int t = c >> 1; // 0=Ahi 1=Alo 2=Bhi 3=Blo
                const int row = ((c & 1) << 6) + srow;
                const __hip_bfloat16* base =
                    (t == 0) ? Ahi + (size_t)(bm * 128) * K :
                    (t == 1) ? Alo + (size_t)(bm * 128) * K :
                    (t == 2) ? Bhi + (size_t)(bn * 128) * K :
                               Blo + (size_t)(bn * 128) * K;
                const __hip_bfloat16* src = base + (size_t)row * K + k0 + (sfetch << 3);
                char* dst = sm + c * 4096 + tid * 16;
                __builtin_amdgcn_global_load_lds((gas_ptr)src, (lds_ptr_t)dst, 16, 0, 0);
            }
        } else {
#pragma unroll
            for (int c = 0; c < 4; ++c) {
                const bool isA = (c < 2);
                const int row = ((c & 1) << 6) + srow;
                const float* src = (isA ? Af + (size_t)(bm * 128 + row) * K
                                        : Bf + (size_t)(bn * 128 + row) * K)
                                   + k0 + ((tid & 3) << 3);
                f32x4 v0 = *(const f32x4*)src;
                f32x4 v1 = *(const f32x4*)(src + 4);
                float vv[8] = {v0.x, v0.y, v0.z, v0.w, v1.x, v1.y, v1.z, v1.w};
                bf16x8 h, l;
#pragma unroll
                for (int j = 0; j < 8; ++j) {
                    unsigned short hb = f32_to_bf16_rtn(vv[j]);
                    unsigned short lb = f32_to_bf16_rtn(vv[j] - bf16_bits_to_f32(hb));
                    h[j] = (short)hb; l[j] = (short)lb;
                }
                // store natural data chunk (tid&3) at swizzled position sfetch
                const int g = row * 64 + sfetch * 16;
                *(bf16x8*)(sm + (isA ? 0 : 16384) + g) = h;
                *(bf16x8*)(sm + (isA ? 8192 : 24576) + g) = l;
            }
        }
        __syncthreads();

#pragma unroll
        for (int kk = 0; kk < 2; ++kk) {
            bf16x8 ah[2], al[2], bh[2], bl[2];
            const int cw = ((kk << 1) + khalf) ^ sw;  // swizzled chunk to read
#pragma unroll
            for (int i = 0; i < 2; ++i) {
                const int ga = (wm + i * 32 + arow) * 64 + cw * 16;
                ah[i] = *(const bf16x8*)(sm +         ga);
                al[i] = *(const bf16x8*)(sm +  8192 + ga);
                const int gb = (wn + i * 32 + arow) * 64 + cw * 16;
                bh[i] = *(const bf16x8*)(sm + 16384 + gb);
                bl[i] = *(const bf16x8*)(sm + 24576 + gb);
            }
#pragma unroll
            for (int i = 0; i < 2; ++i)
#pragma unroll
                for (int j = 0; j < 2; ++j) {
                    acc[i][j] = __builtin_amdgcn_mfma_f32_32x32x16_bf16(ah[i], bh[j], acc[i][j], 0, 0, 0);
                    acc[i][j] = __builtin_amdgcn_mfma_f32_32x32x16_bf16(al[i], bh[j], acc[i][j], 0, 0, 0);
                    acc[i][j] = __builtin_amdgcn_mfma_f32_32x32x16_bf16(ah[i], bl[j], acc[i][j], 0, 0, 0);
                }
        }
    }

    // Epilogue: 32x32 C/D layout col=lane&31, row=(reg&3)+8*(reg>>2)+4*(lane>>5)
    // (m74/m101-verified). 32 consecutive cols per store -> 128B segments.
    const int r0 = bm * 128 + wm + ((lane >> 5) << 2);
    const int c0 = bn * 128 + wn + (lane & 31);
#pragma unroll
    for (int i = 0; i < 2; ++i)
#pragma unroll
        for (int j = 0; j < 2; ++j)
#pragma unroll
            for (int r = 0; r < 16; ++r) {
                const int row = r0 + i * 32 + (r & 3) + ((r >> 2) << 3);
                out[(size_t)row * N + (c0 + j * 32)] = acc[i][j][r];
            }
}

// ---------------------------------------------------------------------------
// Kernel 3: in-place row softmax, one block per row, full row in registers.
// N fixed at 8192: 256 threads x 8 float4. Non-temporal final stores
// (via ext_vector f32x4 — __builtin_nontemporal_store rejects HIP float4).
// ---------------------------------------------------------------------------
__global__ __launch_bounds__(256) void softmax_rows_8192(float* __restrict__ d)
{
    const int tid = threadIdx.x;
    f32x4* p = (f32x4*)(d + (size_t)blockIdx.x * 8192);
    f32x4 v[8];
    float m = -3.402823466e+38f;
#pragma unroll
    for (int i = 0; i < 8; ++i) {
        v[i] = p[tid + (i << 8)];
        m = fmaxf(m, fmaxf(fmaxf(v[i].x, v[i].y), fmaxf(v[i].z, v[i].w)));
    }
#pragma unroll
    for (int o = 32; o >= 1; o >>= 1) m = fmaxf(m, __shfl_xor(m, o));
    __shared__ float smax[4], ssum[4];
    if ((tid & 63) == 0) smax[tid >> 6] = m;
    __syncthreads();
    m = fmaxf(fmaxf(smax[0], smax[1]), fmaxf(smax[2], smax[3]));

    float s = 0.f;
#pragma unroll
    for (int i = 0; i < 8; ++i) {
        v[i].x = __expf(v[i].x - m);
        v[i].y = __expf(v[i].y - m);
        v[i].z = __expf(v[i].z - m);
        v[i].w = __expf(v[i].w - m);
        s += (v[i].x + v[i].y) + (v[i].z + v[i].w);
    }
#pragma unroll
    for (int o = 32; o >= 1; o >>= 1) s += __shfl_xor(s, o);
    if ((tid & 63) == 0) ssum[tid >> 6] = s;
    __syncthreads();
    s = (ssum[0] + ssum[1]) + (ssum[2] + ssum[3]);
    const float r = 1.0f / s;
#pragma unroll
    for (int i = 0; i < 8; ++i) {
        v[i] *= r;
        __builtin_nontemporal_store(v[i], &p[tid + (i << 8)]);
    }
}

// ---------------------------------------------------------------------------
extern "C" void kernel_launch(void* const* d_in, const int* in_sizes, int n_in,
                              void* d_out, int out_size, void* d_ws, size_t ws_size,
                              hipStream_t stream)
{
    const float* A = (const float*)d_in[0];   // user_emb [M, K] fp32
    const float* B = (const float*)d_in[1];   // id_emb   [N, K] fp32
    float* out = (float*)d_out;               // [M, N] fp32
    const int K = 1024;
    const int M = in_sizes[0] / K;
    const int N = in_sizes[1] / K;
    const size_t elemsA = (size_t)M * K;
    const size_t elemsB = (size_t)N * K;
    const size_t need = 2 * (elemsA + elemsB) * sizeof(unsigned short);

    dim3 grid(N / 128, M / 128);
    const bool presplit = (ws_size >= need) && (M == N);

    if (presplit) {
        unsigned short* Ahi = (unsigned short*)d_ws;
        unsigned short* Alo = Ahi + elemsA;
        unsigned short* Bhi = Alo + elemsA;
        unsigned short* Blo = Bhi + elemsB;
        const int n4 = (int)(elemsA / 4);
        split_hi_lo<<<(n4 + 255) / 256, 256, 0, stream>>>(A, B, Ahi, Alo, Bhi, Blo, n4);
        gemm_bt_split<true><<<grid, 256, 0, stream>>>(
            (const __hip_bfloat16*)Ahi, (const __hip_bfloat16*)Alo,
            (const __hip_bfloat16*)Bhi, (const __hip_bfloat16*)Blo,
            nullptr, nullptr, out, M, N, K);
    } else {
        gemm_bt_split<false><<<grid, 256, 0, stream>>>(
            nullptr, nullptr, nullptr, nullptr, A, B, out, M, N, K);
    }
    softmax_rows_8192<<<M, 256, 0, stream>>>(out);
}